// Round 1
// baseline (214.034 us; speedup 1.0000x reference)
//
#include <hip/hip_runtime.h>

typedef unsigned short u16;
typedef unsigned int   u32;
typedef __bf16 bf16x8 __attribute__((ext_vector_type(8)));
typedef float  f32x4  __attribute__((ext_vector_type(4)));

// Geometry (fixed by setup_inputs): b=32, h=w=56, C=192, NH=6, hd=32, WS=7, shift=3
// windows: 32 batches * 8*8 grid = 2048, 49 tokens each (padded to 64)

__device__ __forceinline__ u16 f2b(float f){
  u32 u = __builtin_bit_cast(u32, f);
  u += 0x7FFFu + ((u >> 16) & 1u);
  return (u16)(u >> 16);
}

__global__ __launch_bounds__(256) void prep_kernel(const float* __restrict__ qkvw,
                                                   const float* __restrict__ projw,
                                                   u16* __restrict__ wq, u16* __restrict__ wp){
  const int i = blockIdx.x * 256 + threadIdx.x;
  if (i < 576*192) wq[i] = f2b(qkvw[i]);
  if (i < 192*192) wp[i] = f2b(projw[i]);
}

// ---------------- kernel 1: roll + window-partition + QKV GEMM ----------------
__global__ __launch_bounds__(256) void qkv_kernel(const float* __restrict__ x,
    const u16* __restrict__ wq, const float* __restrict__ qb,
    u16* __restrict__ qO, u16* __restrict__ kO, u16* __restrict__ vT)
{
  __shared__ u16 As[64][200];  // 64 tokens x 192 K (bf16), +8 pad (2-way banks)
  __shared__ u16 Ls[64][72];   // repack buffer: 64 tok x 64 ch chunk
  const int wi = blockIdx.x;                 // 0..2047
  const int bb = wi >> 6, wy = (wi >> 3) & 7, wx = wi & 7;
  const int tid = threadIdx.x;

  // gather A: token (ty,tx) of window (wy,wx) <- x[bb][(wy*7+ty+3)%56][(wx*7+tx+3)%56][:]
  for (int it = tid; it < 64*48; it += 256){
    const int row = it / 48, c4 = (it % 48) * 4;
    u32 p0 = 0, p1 = 0;
    if (row < 49){
      const int ty = row / 7, tx = row % 7;
      int sh = wy*7 + ty + 3; if (sh >= 56) sh -= 56;
      int sw = wx*7 + tx + 3; if (sw >= 56) sw -= 56;
      const float4 f = *reinterpret_cast<const float4*>(x + (size_t)(((bb*56 + sh)*56 + sw))*192 + c4);
      p0 = (u32)f2b(f.x) | ((u32)f2b(f.y) << 16);
      p1 = (u32)f2b(f.z) | ((u32)f2b(f.w) << 16);
    }
    u32* dst = reinterpret_cast<u32*>(&As[row][c4]);
    dst[0] = p0; dst[1] = p1;
  }
  __syncthreads();

  const int wave = tid >> 6, lane = tid & 63;
  const int g = lane >> 4, r = lane & 15;
  const f32x4 z4 = {0.f, 0.f, 0.f, 0.f};

  for (int nc = 0; nc < 9; ++nc){            // 9 N-chunks of 64 output channels
    const int nbase = nc*64 + wave*16;       // this wave's 16-col N-tile
    bf16x8 bfrag[6];
    #pragma unroll
    for (int ks = 0; ks < 6; ++ks)
      bfrag[ks] = *reinterpret_cast<const bf16x8*>(wq + (size_t)(nbase + r)*192 + ks*32 + 8*g);
    f32x4 acc[4] = {z4, z4, z4, z4};
    #pragma unroll
    for (int ks = 0; ks < 6; ++ks){
      #pragma unroll
      for (int mt = 0; mt < 4; ++mt){
        const bf16x8 a = *reinterpret_cast<const bf16x8*>(&As[mt*16 + r][ks*32 + 8*g]);
        acc[mt] = __builtin_amdgcn_mfma_f32_16x16x32_bf16(a, bfrag[ks], acc[mt], 0, 0, 0);
      }
    }
    const float bias = qb[nbase + r];
    const float mul = (nc < 3) ? 0.17677669529663687f : 1.0f;   // q pre-scaled by hd^-0.5
    #pragma unroll
    for (int mt = 0; mt < 4; ++mt)
      #pragma unroll
      for (int jj = 0; jj < 4; ++jj)
        Ls[mt*16 + 4*g + jj][wave*16 + r] = f2b((acc[mt][jj] + bias) * mul);
    __syncthreads();

    if (nc < 6){
      // q or k chunk: rows [tok][d] coalesced copy-out
      for (int un = tid; un < 512; un += 256){
        const int tok = un >> 3, p8 = un & 7;
        const int ch = nc*64 + p8*8;
        u16* dst = (ch < 192) ? qO : kO;
        const int hc = (ch < 192) ? ch : (ch - 192);
        const int u = wi*6 + (hc >> 5);
        const int d0 = hc & 31;
        const uint4 v = *reinterpret_cast<const uint4*>(&Ls[tok][p8*8]);
        *reinterpret_cast<uint4*>(dst + (size_t)(u*64 + tok)*32 + d0) = v;
      }
    } else {
      // v chunk: transpose to vT[u][d][tok] (so attn PV B-frags are contiguous)
      const int ch_l = tid >> 2, tg = tid & 3;
      const int ch = nc*64 + ch_l - 384;
      const int u = wi*6 + (ch >> 5);
      const int d = ch & 31;
      u32 wbuf[8];
      #pragma unroll
      for (int i = 0; i < 8; ++i)
        wbuf[i] = (u32)Ls[tg*16 + 2*i][ch_l] | ((u32)Ls[tg*16 + 2*i + 1][ch_l] << 16);
      uint4 lo = {wbuf[0], wbuf[1], wbuf[2], wbuf[3]};
      uint4 hi = {wbuf[4], wbuf[5], wbuf[6], wbuf[7]};
      u16* base = vT + (size_t)(u*32 + d)*64 + tg*16;
      *reinterpret_cast<uint4*>(base)     = lo;
      *reinterpret_cast<uint4*>(base + 8) = hi;
    }
    __syncthreads();
  }
}

// ---------------- kernel 2: windowed attention ----------------
__device__ __forceinline__ int coords_fn(int t){ return (t/7)*13 + (t%7); }
__device__ __forceinline__ int code_fn(int t, int wy, int wx){
  const int ty = t/7, tx = t%7;
  const int hp = wy*7 + ty, wp = wx*7 + tx;
  const int rh = (hp < 49) ? 0 : ((hp < 53) ? 1 : 2);
  const int rw = (wp < 49) ? 0 : ((wp < 53) ? 1 : 2);
  return rh*3 + rw;
}

__global__ __launch_bounds__(256) void attn_kernel(const u16* __restrict__ q,
    const u16* __restrict__ k, const u16* __restrict__ vT,
    const float* __restrict__ rpb, u16* __restrict__ AO)
{
  __shared__ u16 Ps[4][64][72];          // per-wave P buffer, +8 pad
  const int wave = threadIdx.x >> 6, lane = threadIdx.x & 63;
  const int g = lane >> 4, r = lane & 15;
  const int u = blockIdx.x * 4 + wave;   // exact: 3072*4 = 12288 units
  const int wi = u / 6, head = u % 6;
  const int wy = (wi >> 3) & 7, wx = wi & 7;
  const u16* qp = q  + (size_t)u * 2048;
  const u16* kp = k  + (size_t)u * 2048;
  const u16* vp = vT + (size_t)u * 2048;
  const f32x4 z4 = {0.f, 0.f, 0.f, 0.f};

  bf16x8 aq[4], bk[4];
  #pragma unroll
  for (int t = 0; t < 4; ++t){
    aq[t] = *reinterpret_cast<const bf16x8*>(qp + (t*16 + r)*32 + 8*g);
    bk[t] = *reinterpret_cast<const bf16x8*>(kp + (t*16 + r)*32 + 8*g);
  }
  f32x4 acc[4][4];
  #pragma unroll
  for (int mt = 0; mt < 4; ++mt)
    #pragma unroll
    for (int nt = 0; nt < 4; ++nt)
      acc[mt][nt] = z4;
  #pragma unroll
  for (int nt = 0; nt < 4; ++nt)
    #pragma unroll
    for (int mt = 0; mt < 4; ++mt)
      acc[mt][nt] = __builtin_amdgcn_mfma_f32_16x16x32_bf16(aq[mt], bk[nt], acc[mt][nt], 0, 0, 0);

  // column (key) metadata: j = nt*16 + r
  int cj[4], codej[4]; bool jvalid[4];
  #pragma unroll
  for (int nt = 0; nt < 4; ++nt){
    const int j = nt*16 + r;
    jvalid[nt] = (j < 49);
    const int jc = jvalid[nt] ? (48 - j) : 0;   // reversed rel-pos per reference
    cj[nt] = coords_fn(jc);
    codej[nt] = jvalid[nt] ? code_fn(j, wy, wx) : 0;
  }
  // logits + row max (rows i = mt*16 + 4g + jj live in this lane)
  float mrow[4][4];
  #pragma unroll
  for (int mt = 0; mt < 4; ++mt){
    #pragma unroll
    for (int jj = 0; jj < 4; ++jj){
      int i = mt*16 + 4*g + jj;
      if (i > 48) i = 48;                       // rows >=49 are don't-care
      const int ci = coords_fn(i);
      const int codei = code_fn(i, wy, wx);
      float mx = -1e30f;
      #pragma unroll
      for (int nt = 0; nt < 4; ++nt){
        float lg = -1e30f;
        if (jvalid[nt]){
          lg = acc[mt][nt][jj] + rpb[(ci + cj[nt])*6 + head];
          if (codei != codej[nt]) lg -= 100.0f;
        }
        acc[mt][nt][jj] = lg;
        mx = fmaxf(mx, lg);
      }
      mrow[mt][jj] = mx;
    }
  }
  #pragma unroll
  for (int mt = 0; mt < 4; ++mt)
    #pragma unroll
    for (int jj = 0; jj < 4; ++jj){
      float mx = mrow[mt][jj];
      mx = fmaxf(mx, __shfl_xor(mx, 1));
      mx = fmaxf(mx, __shfl_xor(mx, 2));
      mx = fmaxf(mx, __shfl_xor(mx, 4));
      mx = fmaxf(mx, __shfl_xor(mx, 8));
      mrow[mt][jj] = mx;
    }
  float rs[4][4];
  #pragma unroll
  for (int mt = 0; mt < 4; ++mt)
    #pragma unroll
    for (int jj = 0; jj < 4; ++jj){
      float s = 0.0f;
      #pragma unroll
      for (int nt = 0; nt < 4; ++nt){
        const float p = __expf(acc[mt][nt][jj] - mrow[mt][jj]);
        acc[mt][nt][jj] = p;
        s += p;
      }
      s += __shfl_xor(s, 1);
      s += __shfl_xor(s, 2);
      s += __shfl_xor(s, 4);
      s += __shfl_xor(s, 8);
      rs[mt][jj] = 1.0f / s;
    }
  // normalized P -> LDS (bf16)
  #pragma unroll
  for (int mt = 0; mt < 4; ++mt)
    #pragma unroll
    for (int nt = 0; nt < 4; ++nt)
      #pragma unroll
      for (int jj = 0; jj < 4; ++jj)
        Ps[wave][mt*16 + 4*g + jj][nt*16 + r] = f2b(acc[mt][nt][jj] * rs[mt][jj]);
  __syncthreads();

  // PV: O = P(64x64) @ v(64x32); B-frags contiguous from vT
  bf16x8 bv[2][2];
  #pragma unroll
  for (int nt = 0; nt < 2; ++nt)
    #pragma unroll
    for (int ks = 0; ks < 2; ++ks)
      bv[nt][ks] = *reinterpret_cast<const bf16x8*>(vp + (nt*16 + r)*64 + ks*32 + 8*g);
  f32x4 o[4][2];
  #pragma unroll
  for (int mt = 0; mt < 4; ++mt){ o[mt][0] = z4; o[mt][1] = z4; }
  #pragma unroll
  for (int mt = 0; mt < 4; ++mt){
    #pragma unroll
    for (int ks = 0; ks < 2; ++ks){
      const bf16x8 ap = *reinterpret_cast<const bf16x8*>(&Ps[wave][mt*16 + r][ks*32 + 8*g]);
      #pragma unroll
      for (int nt = 0; nt < 2; ++nt)
        o[mt][nt] = __builtin_amdgcn_mfma_f32_16x16x32_bf16(ap, bv[nt][ks], o[mt][nt], 0, 0, 0);
    }
  }
  // write AO[wi][tok][head*32+d] (rows < 49 only)
  #pragma unroll
  for (int mt = 0; mt < 4; ++mt)
    #pragma unroll
    for (int jj = 0; jj < 4; ++jj){
      const int tok = mt*16 + 4*g + jj;
      if (tok < 49){
        #pragma unroll
        for (int nt = 0; nt < 2; ++nt)
          AO[(size_t)(wi*64 + tok)*192 + head*32 + nt*16 + r] = f2b(o[mt][nt][jj]);
      }
    }
}

// ---------------- kernel 3: output projection + window-reverse + roll-back ----------------
__global__ __launch_bounds__(256) void proj_kernel(const u16* __restrict__ AO,
    const u16* __restrict__ wp, const float* __restrict__ pb, float* __restrict__ out)
{
  __shared__ u16 As[64][200];
  const int wi = blockIdx.x, tid = threadIdx.x;
  const int bb = wi >> 6, wy = (wi >> 3) & 7, wx = wi & 7;
  for (int it = tid; it < 64*24; it += 256){
    const int row = it / 24, c8 = (it % 24) * 8;
    *reinterpret_cast<uint4*>(&As[row][c8]) =
      *reinterpret_cast<const uint4*>(AO + (size_t)(wi*64 + row)*192 + c8);
  }
  __syncthreads();
  const int wave = tid >> 6, lane = tid & 63;
  const int g = lane >> 4, r = lane & 15;
  const f32x4 z4 = {0.f, 0.f, 0.f, 0.f};
  f32x4 acc[4][3];
  #pragma unroll
  for (int mt = 0; mt < 4; ++mt){ acc[mt][0] = z4; acc[mt][1] = z4; acc[mt][2] = z4; }
  #pragma unroll
  for (int nt = 0; nt < 3; ++nt){
    const int nb = wave*48 + nt*16;
    #pragma unroll
    for (int ks = 0; ks < 6; ++ks){
      const bf16x8 bw = *reinterpret_cast<const bf16x8*>(wp + (size_t)(nb + r)*192 + ks*32 + 8*g);
      #pragma unroll
      for (int mt = 0; mt < 4; ++mt){
        const bf16x8 a = *reinterpret_cast<const bf16x8*>(&As[mt*16 + r][ks*32 + 8*g]);
        acc[mt][nt] = __builtin_amdgcn_mfma_f32_16x16x32_bf16(a, bw, acc[mt][nt], 0, 0, 0);
      }
    }
  }
  #pragma unroll
  for (int nt = 0; nt < 3; ++nt){
    const int n = wave*48 + nt*16 + r;
    const float bias = pb[n];
    #pragma unroll
    for (int mt = 0; mt < 4; ++mt){
      #pragma unroll
      for (int jj = 0; jj < 4; ++jj){
        const int tok = mt*16 + 4*g + jj;
        if (tok < 49){
          const int ty = tok/7, tx = tok%7;
          int dh = wy*7 + ty + 3; if (dh >= 56) dh -= 56;
          int dw = wx*7 + tx + 3; if (dw >= 56) dw -= 56;
          out[(size_t)((bb*56 + dh)*56 + dw)*192 + n] = acc[mt][nt][jj] + bias;
        }
      }
    }
  }
}

extern "C" void kernel_launch(void* const* d_in, const int* in_sizes, int n_in,
                              void* d_out, int out_size, void* d_ws, size_t ws_size,
                              hipStream_t stream) {
  const float* x     = (const float*)d_in[0];
  const float* rpb   = (const float*)d_in[1];
  const float* qkvw  = (const float*)d_in[2];
  const float* qkvb  = (const float*)d_in[3];
  const float* projw = (const float*)d_in[4];
  const float* projb = (const float*)d_in[5];
  float* out = (float*)d_out;

  char* ws = (char*)d_ws;
  // workspace layout (bytes):
  //   wq  bf16 [576][192]              @ 0         (221184)
  //   wp  bf16 [192][192]              @ 221184    (73728)
  //   q   bf16 [12288][64][32]         @ 294912    (50331648)
  //   k   bf16 [12288][64][32]         @ +1x       (50331648)
  //   vT  bf16 [12288][32][64]         @ +2x       (50331648)
  //   AO  bf16 [2048][64][192]         @ +3x       (50331648)   total ~192.3 MiB
  u16* wq  = (u16*)(ws);
  u16* wpj = (u16*)(ws + 221184);
  u16* qB  = (u16*)(ws + 294912);
  u16* kB  = (u16*)(ws + 294912 + 1ll*50331648);
  u16* vT  = (u16*)(ws + 294912 + 2ll*50331648);
  u16* AO  = (u16*)(ws + 294912 + 3ll*50331648);

  prep_kernel<<<432, 256, 0, stream>>>(qkvw, projw, wq, wpj);
  qkv_kernel <<<2048, 256, 0, stream>>>(x, wq, qkvb, qB, kB, vT);
  attn_kernel<<<3072, 256, 0, stream>>>(qB, kB, vT, rpb, AO);
  proj_kernel<<<2048, 256, 0, stream>>>(AO, wpj, projb, out);
}